// Round 3
// baseline (972.738 us; speedup 1.0000x reference)
//
#include <hip/hip_runtime.h>
#include <math.h>

#define N_U 100000
#define N_V 100000
#define D 128
#define E1 3200000
#define E2 3200000
#define ETOT (E1 + E2)

#define NBUCK 196      // buckets of 512 dst nodes: dst >> 9
#define SLACK 35000    // per-bucket record capacity (expected 32768 +/- ~180)
#define PCHUNK 4096    // edges per partition block
#define NHALF 50000    // source-half split point

typedef __bf16 bf16x8 __attribute__((ext_vector_type(8)));
typedef float f32x4 __attribute__((ext_vector_type(4)));

__device__ __forceinline__ unsigned short f2b(float f) {
  union { float f; unsigned int u; } v; v.f = f;
  unsigned int u = v.u;
  unsigned int r = u + 0x7fffu + ((u >> 16) & 1u);
  return (unsigned short)(r >> 16);
}
__device__ __forceinline__ float b2f(unsigned short s) {
  union { unsigned int u; float f; } v; v.u = ((unsigned int)s) << 16; return v.f;
}
// packed-bf16 dword -> two floats (2 VALU ops total)
__device__ __forceinline__ float b2f_lo(unsigned w) {
  union { unsigned u; float f; } v; v.u = w << 16; return v.f;
}
__device__ __forceinline__ float b2f_hi(unsigned w) {
  union { unsigned u; float f; } v; v.u = w & 0xffff0000u; return v.f;
}

// ---------------------------------------------------------------------------
// Weight transpose+bf16: WT[n][k] = bf16(W[k][n])
// ---------------------------------------------------------------------------
__global__ void convert_w128(const float* __restrict__ W, unsigned short* __restrict__ WT) {
  int idx = blockIdx.x * 256 + threadIdx.x;
  if (idx < 128 * 128) {
    int n = idx >> 7, k = idx & 127;
    WT[idx] = f2b(W[k * 128 + n]);
  }
}
__global__ void convert_wg(const float* __restrict__ Wg, unsigned short* __restrict__ WgT) {
  int idx = blockIdx.x * 256 + threadIdx.x;
  if (idx < 384 * 384) {
    int n = idx / 384, k = idx - n * 384;
    WgT[idx] = f2b(Wg[k * 384 + n]);
  }
}
__global__ void convert_wa(const float* __restrict__ Wa, unsigned short* __restrict__ WaT) {
  int idx = blockIdx.x * 256 + threadIdx.x;
  if (idx < 128 * 384) {
    int n = idx / 384, k = idx - n * 384;
    WaT[idx] = f2b(Wa[k * 128 + n]);
  }
}

// ---------------------------------------------------------------------------
// Linear: Hb(bf16) = X(fp32) @ W  via MFMA. 64 rows/block, 4 waves x 16 rows.
// ---------------------------------------------------------------------------
#define LM 64
__global__ __launch_bounds__(256) void linear_mfma(
    const float* __restrict__ X, const unsigned short* __restrict__ WT,
    unsigned short* __restrict__ Hb, int nrows) {
  __shared__ unsigned short Xs[LM][136];
  const int t = threadIdx.x;
  const int row0 = blockIdx.x * LM;

  for (int i = t * 4; i < LM * 128; i += 1024) {
    int n = i >> 7, j = i & 127;
    int r = row0 + n;
    float4 v = make_float4(0.f, 0.f, 0.f, 0.f);
    if (r < nrows) v = *(const float4*)&X[(size_t)r * 128 + j];
    Xs[n][j] = f2b(v.x);
    Xs[n][j + 1] = f2b(v.y);
    Xs[n][j + 2] = f2b(v.z);
    Xs[n][j + 3] = f2b(v.w);
  }
  __syncthreads();

  const int wv = t >> 6;
  const int ln = t & 63;
  const int lr = ln & 15;
  const int lq = ln >> 4;
  const int m0 = wv * 16;

  bf16x8 a[4];
#pragma unroll
  for (int ks = 0; ks < 4; ks++)
    a[ks] = *(const bf16x8*)&Xs[m0 + lr][ks * 32 + lq * 8];

#pragma unroll
  for (int np = 0; np < 4; np++) {
    const int n0 = np * 32;
    f32x4 acc0 = {0.f, 0.f, 0.f, 0.f};
    f32x4 acc1 = {0.f, 0.f, 0.f, 0.f};
    const unsigned short* B0 = &WT[(size_t)(n0 + lr) * 128 + lq * 8];
    const unsigned short* B1 = B0 + 16 * 128;
#pragma unroll
    for (int ks = 0; ks < 4; ks++) {
      bf16x8 b0 = *(const bf16x8*)(B0 + ks * 32);
      bf16x8 b1 = *(const bf16x8*)(B1 + ks * 32);
      acc0 = __builtin_amdgcn_mfma_f32_16x16x32_bf16(a[ks], b0, acc0, 0, 0, 0);
      acc1 = __builtin_amdgcn_mfma_f32_16x16x32_bf16(a[ks], b1, acc1, 0, 0, 0);
    }
#pragma unroll
    for (int r = 0; r < 4; r++) {
      int grow = row0 + m0 + lq * 4 + r;
      if (grow < nrows) {
        Hb[(size_t)grow * 128 + n0 + lr] = f2b(acc0[r]);
        Hb[(size_t)grow * 128 + n0 + 16 + lr] = f2b(acc1[r]);
      }
    }
  }
}

// ---------------------------------------------------------------------------
// Partition: 4096 edges/block -> LDS hist -> reserve slack ranges -> LDS-stage
// bucket-ordered -> coalesced flush of (enc, dst) into per-bucket slack region.
// ---------------------------------------------------------------------------
__global__ __launch_bounds__(256) void partition_kernel(
    const int* __restrict__ e1, const int* __restrict__ e2,
    int* __restrict__ bucketCursor, uint2* __restrict__ recs) {
  __shared__ int hist[256];
  __shared__ int scan_s[256];
  __shared__ int lstart[256];
  __shared__ int gbase[NBUCK];
  __shared__ int lcur[NBUCK];
  __shared__ uint2 buf[PCHUNK];  // 32 KB

  const int t = threadIdx.x;
  const long base = (long)blockIdx.x * PCHUNK;
  const int n = (int)min((long)PCHUNK, (long)ETOT - base);

  hist[t] = 0;
  __syncthreads();

  uint2 myrec[PCHUNK / 256];
  int myb[PCHUNK / 256];
  int cnt = 0;
#pragma unroll
  for (int k = 0; k < PCHUNK / 256; k++) {
    int idx = t + k * 256;
    if (idx < n) {
      long i = base + idx;
      int enc, dst;
      if (i < E1) {
        dst = e1[E1 + i];
        enc = N_V + e1[i];
      } else {
        long j = i - E1;
        dst = e2[E2 + j];
        enc = e2[j];
      }
      myrec[cnt] = make_uint2((unsigned)enc, (unsigned)dst);
      int b = dst >> 9;
      myb[cnt] = b;
      atomicAdd(&hist[b], 1);
      cnt++;
    }
  }
  __syncthreads();

  int v = hist[t];
  scan_s[t] = v;
  __syncthreads();
  for (int off = 1; off < 256; off <<= 1) {
    int tmp = (t >= off) ? scan_s[t - off] : 0;
    __syncthreads();
    scan_s[t] += tmp;
    __syncthreads();
  }
  lstart[t] = scan_s[t] - v;
  if (t < NBUCK) {
    gbase[t] = atomicAdd(&bucketCursor[t], v);
    lcur[t] = scan_s[t] - v;
  }
  __syncthreads();

  for (int k = 0; k < cnt; k++) {
    int p = atomicAdd(&lcur[myb[k]], 1);
    buf[p] = myrec[k];
  }
  __syncthreads();

  for (int p = t; p < n; p += 256) {
    uint2 r = buf[p];
    int b = (int)(r.y >> 9);
    recs[(size_t)b * SLACK + gbase[b] + (p - lstart[b])] = r;
  }
}

// Scan bucket counts -> compact bases.
__global__ __launch_bounds__(256) void bucket_scan(
    const int* __restrict__ bucketCnt, int* __restrict__ bucketBase) {
  __shared__ int s[256];
  const int t = threadIdx.x;
  int v = (t < NBUCK) ? bucketCnt[t] : 0;
  s[t] = v;
  __syncthreads();
  for (int off = 1; off < 256; off <<= 1) {
    int tmp = (t >= off) ? s[t - off] : 0;
    __syncthreads();
    s[t] += tmp;
    __syncthreads();
  }
  if (t < NBUCK) bucketBase[t] = s[t] - v;
  if (t == 255) bucketBase[NBUCK] = s[255];
}

// One block per bucket: per-node 4-category hist+scan -> row_ptr; each node's
// segment ordered [r2-srcLo | r2-srcHi | r1-srcLo | r1-srcHi] so the aggregate
// walk touches a 3.2MB (half-table x quarter-feats) hot set at a time.
// col holds BYTE offsets into Hb (enc*256).
__global__ __launch_bounds__(512) void bucket_fill(
    const uint2* __restrict__ recs, const int* __restrict__ bucketCnt,
    const int* __restrict__ bucketBase, int* __restrict__ row_ptr,
    int* __restrict__ col) {
  __shared__ int hist4[512 * 4];  // [node][cat]
  __shared__ int s[512];
  __shared__ int cur4[512 * 4];
  const int t = threadIdx.x;
  const int b = blockIdx.x;
  const size_t slack = (size_t)b * SLACK;
  const int n = bucketCnt[b];
  const int outBase = bucketBase[b];
  const int n0 = b << 9;

#pragma unroll
  for (int c = 0; c < 4; c++) hist4[t * 4 + c] = 0;
  __syncthreads();
  for (int p = t; p < n; p += 512) {
    uint2 r = recs[slack + p];
    int local = (int)r.y - n0;
    unsigned enc = r.x;
    int cat = (enc >= (unsigned)N_V)
                  ? ((enc >= (unsigned)(N_V + NHALF)) ? 3 : 2)
                  : ((enc >= (unsigned)NHALF) ? 1 : 0);
    atomicAdd(&hist4[local * 4 + cat], 1);
  }
  __syncthreads();

  int c0 = hist4[t * 4], c1 = hist4[t * 4 + 1];
  int c2 = hist4[t * 4 + 2], c3 = hist4[t * 4 + 3];
  int v = c0 + c1 + c2 + c3;
  s[t] = v;
  __syncthreads();
  for (int off = 1; off < 512; off <<= 1) {
    int tmp = (t >= off) ? s[t - off] : 0;
    __syncthreads();
    s[t] += tmp;
    __syncthreads();
  }
  int excl = s[t] - v;
  cur4[t * 4 + 0] = excl;
  cur4[t * 4 + 1] = excl + c0;
  cur4[t * 4 + 2] = excl + c0 + c1;
  cur4[t * 4 + 3] = excl + c0 + c1 + c2;
  int nd = n0 + t;
  if (nd < N_V) row_ptr[nd] = outBase + excl;
  if (b == 0 && t == 0) row_ptr[N_V] = ETOT;
  __syncthreads();

  for (int p = t; p < n; p += 512) {
    uint2 r = recs[slack + p];
    int local = (int)r.y - n0;
    unsigned enc = r.x;
    int cat = (enc >= (unsigned)N_V)
                  ? ((enc >= (unsigned)(N_V + NHALF)) ? 3 : 2)
                  : ((enc >= (unsigned)NHALF) ? 1 : 0);
    int q = atomicAdd(&cur4[local * 4 + cat], 1);
    col[outBase + q] = (int)(enc << 8);  // byte offset of Hb row
  }
}

// ---------------------------------------------------------------------------
// Aggregation v3: feature-quartered gather to fit the L2.
// Block = 4 nodes (4 waves). The contiguous col-segment of the 4 nodes is
// cached in LDS once. Outer loop fp=0..3 walks the segment reading only a
// 64B quarter-row per edge; combined with bucket_fill's 4-category ordering
// the instantaneous hot set is 50K rows x 64B = 3.2MB < 4MiB per-XCD L2.
// Lane layout per wave: grp = lane>>4 picks edge-in-group-of-4, fl = lane&15
// picks the dword (feats 32*fp+2*fl, +1). Per-feature accumulation order is
// identical to v2 (groups g=0..7, then shfl_xor 16/32 reduce).
// ---------------------------------------------------------------------------
__global__ __launch_bounds__(256) void aggregate_kernel(
    const unsigned short* __restrict__ Hb, const int* __restrict__ row_ptr,
    const int* __restrict__ col, unsigned int* __restrict__ SumB,
    unsigned int* __restrict__ MxB) {
  __shared__ int cix[1024];
  const int t = threadIdx.x;
  const int node0 = blockIdx.x * 4;
  const int node = node0 + (t >> 6);
  const int lane = t & 63;
  const int grp = lane >> 4;
  const int fl = lane & 15;
  const char* Hc = (const char*)Hb;

  const int blkStart = row_ptr[node0];
  const int blkEnd = row_ptr[node0 + 4];
  const int total = blkEnd - blkStart;

  const int* csrc;
  if (total <= 1024) {
    for (int p = t; p < total; p += 256) cix[p] = col[blkStart + p];
    csrc = cix;                 // generic pointer into LDS
  } else {
    csrc = col + blkStart;      // fallback (statistically never)
  }
  __syncthreads();

  const int start = row_ptr[node] - blkStart;
  const int end = row_ptr[node + 1] - blkStart;

  for (int fp = 0; fp < 4; fp++) {
    const int boff = fp * 64 + fl * 4;
    float s0 = 0.f, s1 = 0.f, m0 = 0.f, m1 = 0.f;

    int i = start;
    for (; i + 31 < end; i += 32) {
      unsigned v[8];
#pragma unroll
      for (int g = 0; g < 8; g++)
        v[g] = *(const unsigned*)(Hc + (unsigned)csrc[i + g * 4 + grp] + boff);
#pragma unroll
      for (int g = 0; g < 8; g++) {
        float lo = b2f_lo(v[g]), hi = b2f_hi(v[g]);
        s0 += lo; s1 += hi;
        m0 = fmaxf(m0, lo); m1 = fmaxf(m1, hi);
      }
    }
    for (; i < end; i += 4) {
      int e = i + grp;
      int ec = e < end ? e : (end - 1);
      unsigned v = *(const unsigned*)(Hc + (unsigned)csrc[ec] + boff);
      if (e >= end) v = 0u;
      float lo = b2f_lo(v), hi = b2f_hi(v);
      s0 += lo; s1 += hi;
      m0 = fmaxf(m0, lo); m1 = fmaxf(m1, hi);
    }

    // reduce across the 4 edge-groups (butterfly -> all lanes hold result)
    s0 += __shfl_xor(s0, 16, 64); m0 = fmaxf(m0, __shfl_xor(m0, 16, 64));
    s1 += __shfl_xor(s1, 16, 64); m1 = fmaxf(m1, __shfl_xor(m1, 16, 64));
    s0 += __shfl_xor(s0, 32, 64); m0 = fmaxf(m0, __shfl_xor(m0, 32, 64));
    s1 += __shfl_xor(s1, 32, 64); m1 = fmaxf(m1, __shfl_xor(m1, 32, 64));

    if (lane < 16) {
      SumB[(size_t)node * 64 + fp * 16 + fl] =
          (unsigned)f2b(s0) | ((unsigned)f2b(s1) << 16);
    } else if (lane < 32) {
      MxB[(size_t)node * 64 + fp * 16 + fl] =
          (unsigned)f2b(m0) | ((unsigned)f2b(m1) << 16);
    }
  }
}

// ---------------------------------------------------------------------------
// MFMA epilogue v4: global B-fragment loads software-pipelined one kc ahead
// (bA/bB rotation, static names) so L2 latency hides under the MFMA cluster.
// ---------------------------------------------------------------------------
#define EM 64
__global__ __launch_bounds__(256, 3) void epilogue_mfma(
    const unsigned short* __restrict__ SumB, const unsigned short* __restrict__ MxB,
    const int* __restrict__ row_ptr, const unsigned short* __restrict__ Wg16,
    const float* __restrict__ bg, const unsigned short* __restrict__ Wa16,
    const float* __restrict__ ba, float* __restrict__ Out) {
  __shared__ unsigned short Ts[EM][392];   // 50176 B
  __shared__ float invs[EM];
  __shared__ int cnts[EM];

  const int t = threadIdx.x;
  const int node0 = blockIdx.x * EM;

  if (t < EM) {
    int nd = node0 + t;
    int c = 0;
    if (nd < N_V) c = row_ptr[nd + 1] - row_ptr[nd];
    cnts[t] = c;
    invs[t] = 1.0f / (float)(c > 0 ? c : 1);
  }
  __syncthreads();

  // Build Ts = [sum(128) | mean(128) | max(128)] bf16, 16B-vectorized.
  {
    const uint4* Sv = (const uint4*)SumB;
    const uint4* Mv = (const uint4*)MxB;
    for (int i = t; i < EM * 16; i += 256) {
      int n = i >> 4, u = i & 15;
      int nd = node0 + n;
      uint4 s = make_uint4(0u, 0u, 0u, 0u);
      uint4 m4 = make_uint4(0u, 0u, 0u, 0u);
      if (nd < N_V) {
        s = Sv[(size_t)nd * 16 + u];
        m4 = Mv[(size_t)nd * 16 + u];
      }
      float inv = invs[n];
      *(uint4*)&Ts[n][u * 8] = s;
      unsigned sw[4] = {s.x, s.y, s.z, s.w};
      unsigned mr[4];
#pragma unroll
      for (int q = 0; q < 4; q++) {
        unsigned short lo = f2b(b2f((unsigned short)sw[q]) * inv);
        unsigned short hi = f2b(b2f((unsigned short)(sw[q] >> 16)) * inv);
        mr[q] = (unsigned)lo | ((unsigned)hi << 16);
      }
      *(uint4*)&Ts[n][128 + u * 8] = make_uint4(mr[0], mr[1], mr[2], mr[3]);
      *(uint4*)&Ts[n][256 + u * 8] = m4;
    }
  }
  __syncthreads();

  const int wv = t >> 6;
  const int ln = t & 63;
  const int lr = ln & 15;
  const int lq = ln >> 4;

  // ---- Gate GEMM: acc[m][nt], rows m*16+lq*4+r, cols wv*96+nt*16+lr ----
  f32x4 acc[4][6];
#pragma unroll
  for (int m = 0; m < 4; m++)
#pragma unroll
    for (int nt = 0; nt < 6; nt++) acc[m][nt] = (f32x4){0.f, 0.f, 0.f, 0.f};

  const unsigned short* Bg = Wg16 + (size_t)(wv * 96 + lr) * 384 + lq * 8;

  {
    bf16x8 bA[6], bB[6];
#pragma unroll
    for (int nt = 0; nt < 6; nt++)
      bA[nt] = *(const bf16x8*)(Bg + nt * (16 * 384));
    for (int kc = 0; kc < 12; kc += 2) {
#pragma unroll
      for (int nt = 0; nt < 6; nt++)
        bB[nt] = *(const bf16x8*)(Bg + nt * (16 * 384) + (kc + 1) * 32);
      bf16x8 a0[4];
#pragma unroll
      for (int m = 0; m < 4; m++)
        a0[m] = *(const bf16x8*)&Ts[m * 16 + lr][kc * 32 + lq * 8];
#pragma unroll
      for (int m = 0; m < 4; m++)
#pragma unroll
        for (int nt = 0; nt < 6; nt++)
          acc[m][nt] = __builtin_amdgcn_mfma_f32_16x16x32_bf16(a0[m], bA[nt], acc[m][nt], 0, 0, 0);
      if (kc + 2 < 12) {
#pragma unroll
        for (int nt = 0; nt < 6; nt++)
          bA[nt] = *(const bf16x8*)(Bg + nt * (16 * 384) + (kc + 2) * 32);
      }
      bf16x8 a1[4];
#pragma unroll
      for (int m = 0; m < 4; m++)
        a1[m] = *(const bf16x8*)&Ts[m * 16 + lr][(kc + 1) * 32 + lq * 8];
#pragma unroll
      for (int m = 0; m < 4; m++)
#pragma unroll
        for (int nt = 0; nt < 6; nt++)
          acc[m][nt] = __builtin_amdgcn_mfma_f32_16x16x32_bf16(a1[m], bB[nt], acc[m][nt], 0, 0, 0);
    }
  }
  __syncthreads();  // all Ts reads done before gated rewrite

  // Gate apply: wave wv owns cols [wv*96, wv*96+96), all 64 rows.
#pragma unroll
  for (int nt = 0; nt < 6; nt++) {
    int cg = wv * 96 + nt * 16 + lr;
    float bgv = bg[cg];
#pragma unroll
    for (int m = 0; m < 4; m++) {
#pragma unroll
      for (int r = 0; r < 4; r++) {
        int row = m * 16 + lq * 4 + r;
        float g = 1.f / (1.f + __expf(-(acc[m][nt][r] + bgv)));
        Ts[row][cg] = f2b(b2f(Ts[row][cg]) * g);
      }
    }
  }
  __syncthreads();  // gated Ts ready for aggr GEMM

  // ---- Aggr GEMM: acc2[m][nt], cols wv*32+nt*16+lr ----
  f32x4 acc2[4][2];
#pragma unroll
  for (int m = 0; m < 4; m++)
#pragma unroll
    for (int nt = 0; nt < 2; nt++) acc2[m][nt] = (f32x4){0.f, 0.f, 0.f, 0.f};

  const unsigned short* Ba = Wa16 + (size_t)(wv * 32 + lr) * 384 + lq * 8;

  {
    bf16x8 bA[2], bB[2];
#pragma unroll
    for (int nt = 0; nt < 2; nt++)
      bA[nt] = *(const bf16x8*)(Ba + nt * (16 * 384));
    for (int kc = 0; kc < 12; kc += 2) {
#pragma unroll
      for (int nt = 0; nt < 2; nt++)
        bB[nt] = *(const bf16x8*)(Ba + nt * (16 * 384) + (kc + 1) * 32);
      bf16x8 a0[4];
#pragma unroll
      for (int m = 0; m < 4; m++)
        a0[m] = *(const bf16x8*)&Ts[m * 16 + lr][kc * 32 + lq * 8];
#pragma unroll
      for (int m = 0; m < 4; m++)
#pragma unroll
        for (int nt = 0; nt < 2; nt++)
          acc2[m][nt] = __builtin_amdgcn_mfma_f32_16x16x32_bf16(a0[m], bA[nt], acc2[m][nt], 0, 0, 0);
      if (kc + 2 < 12) {
#pragma unroll
        for (int nt = 0; nt < 2; nt++)
          bA[nt] = *(const bf16x8*)(Ba + nt * (16 * 384) + (kc + 2) * 32);
      }
      bf16x8 a1[4];
#pragma unroll
      for (int m = 0; m < 4; m++)
        a1[m] = *(const bf16x8*)&Ts[m * 16 + lr][(kc + 1) * 32 + lq * 8];
#pragma unroll
      for (int m = 0; m < 4; m++)
#pragma unroll
        for (int nt = 0; nt < 2; nt++)
          acc2[m][nt] = __builtin_amdgcn_mfma_f32_16x16x32_bf16(a1[m], bB[nt], acc2[m][nt], 0, 0, 0);
    }
  }

#pragma unroll
  for (int nt = 0; nt < 2; nt++) {
    int cg = wv * 32 + nt * 16 + lr;
    float bav = ba[cg];
#pragma unroll
    for (int m = 0; m < 4; m++) {
#pragma unroll
      for (int r = 0; r < 4; r++) {
        int row = m * 16 + lq * 4 + r;
        int nd = node0 + row;
        if (nd < N_V) {
          float msk = (cnts[row] > 0) ? 1.f : 0.f;
          Out[(size_t)nd * D + cg] = (acc2[m][nt][r] + bav) * msk;
        }
      }
    }
  }
}

// ---------------------------------------------------------------------------
extern "C" void kernel_launch(void* const* d_in, const int* in_sizes, int n_in,
                              void* d_out, int out_size, void* d_ws, size_t ws_size,
                              hipStream_t stream) {
  const float* x_u = (const float*)d_in[0];
  const float* x_v = (const float*)d_in[1];
  const float* W_r1 = (const float*)d_in[2];
  const float* W_r2 = (const float*)d_in[3];
  const float* W_gate = (const float*)d_in[4];
  const float* b_gate = (const float*)d_in[5];
  const float* W_aggr = (const float*)d_in[6];
  const float* b_aggr = (const float*)d_in[7];
  const int* e1 = (const int*)d_in[8];
  const int* e2 = (const int*)d_in[9];
  float* out = (float*)d_out;

  char* ws = (char*)d_ws;
  size_t off = 0;
  unsigned short* Hb = (unsigned short*)(ws + off); off += (size_t)(N_V + N_U) * D * 2;
  unsigned int* SumB = (unsigned int*)(ws + off);   off += (size_t)N_V * D * 2;
  unsigned int* MxB = (unsigned int*)(ws + off);    off += (size_t)N_V * D * 2;
  int* colA = (int*)(ws + off);        off += (size_t)ETOT * 4;
  uint2* recs = (uint2*)(ws + off);    off += (size_t)NBUCK * SLACK * 8;
  int* row_ptr = (int*)(ws + off);     off += (size_t)(N_V + 1) * 4;
  int* bucketCursor = (int*)(ws + off); off += NBUCK * 4;
  int* bucketBase = (int*)(ws + off);  off += (NBUCK + 1) * 4;
  unsigned short* Wg16 = (unsigned short*)(ws + off); off += (size_t)384 * 384 * 2;
  unsigned short* Wa16 = (unsigned short*)(ws + off); off += (size_t)128 * 384 * 2;
  unsigned short* Wr1T = (unsigned short*)(ws + off); off += (size_t)128 * 128 * 2;
  unsigned short* Wr2T = (unsigned short*)(ws + off); off += (size_t)128 * 128 * 2;

  hipMemsetAsync(bucketCursor, 0, NBUCK * 4, stream);

  convert_w128<<<64, 256, 0, stream>>>(W_r1, Wr1T);
  convert_w128<<<64, 256, 0, stream>>>(W_r2, Wr2T);
  convert_wg<<<(384 * 384 + 255) / 256, 256, 0, stream>>>(W_gate, Wg16);
  convert_wa<<<(128 * 384 + 255) / 256, 256, 0, stream>>>(W_aggr, Wa16);

  linear_mfma<<<(N_V + LM - 1) / LM, 256, 0, stream>>>(x_v, Wr2T, Hb, N_V);
  linear_mfma<<<(N_U + LM - 1) / LM, 256, 0, stream>>>(x_u, Wr1T, Hb + (size_t)N_V * D, N_U);

  partition_kernel<<<(ETOT + PCHUNK - 1) / PCHUNK, 256, 0, stream>>>(
      e1, e2, bucketCursor, recs);
  bucket_scan<<<1, 256, 0, stream>>>(bucketCursor, bucketBase);
  bucket_fill<<<NBUCK, 512, 0, stream>>>(recs, bucketCursor, bucketBase, row_ptr, colA);

  aggregate_kernel<<<N_V / 4, 256, 0, stream>>>(Hb, row_ptr, colA, SumB, MxB);

  epilogue_mfma<<<(N_V + EM - 1) / EM, 256, 0, stream>>>(
      (const unsigned short*)SumB, (const unsigned short*)MxB, row_ptr,
      Wg16, b_gate, Wa16, b_aggr, out);
}

// Round 4
// 739.749 us; speedup vs baseline: 1.3150x; 1.3150x over previous
//
#include <hip/hip_runtime.h>
#include <math.h>

#define N_U 100000
#define N_V 100000
#define D 128
#define E1 3200000
#define E2 3200000
#define ETOT (E1 + E2)

#define NBUCK 196      // buckets of 512 dst nodes: dst >> 9
#define SLACK 35000    // per-bucket record capacity (expected 32768 +/- ~180)
#define PCHUNK 4096    // edges per partition block
#define NCAT 16        // ordering categories: relation x src-eighth
#define SRCW 12500     // rows per src-eighth (100000/8)

typedef __bf16 bf16x8 __attribute__((ext_vector_type(8)));
typedef float f32x4 __attribute__((ext_vector_type(4)));

__device__ __forceinline__ unsigned short f2b(float f) {
  union { float f; unsigned int u; } v; v.f = f;
  unsigned int u = v.u;
  unsigned int r = u + 0x7fffu + ((u >> 16) & 1u);
  return (unsigned short)(r >> 16);
}
__device__ __forceinline__ float b2f(unsigned short s) {
  union { unsigned int u; float f; } v; v.u = ((unsigned int)s) << 16; return v.f;
}
// packed-bf16 dword -> two floats (2 VALU ops total)
__device__ __forceinline__ float b2f_lo(unsigned w) {
  union { unsigned u; float f; } v; v.u = w << 16; return v.f;
}
__device__ __forceinline__ float b2f_hi(unsigned w) {
  union { unsigned u; float f; } v; v.u = w & 0xffff0000u; return v.f;
}

// ---------------------------------------------------------------------------
// Weight transpose+bf16: WT[n][k] = bf16(W[k][n])
// ---------------------------------------------------------------------------
__global__ void convert_w128(const float* __restrict__ W, unsigned short* __restrict__ WT) {
  int idx = blockIdx.x * 256 + threadIdx.x;
  if (idx < 128 * 128) {
    int n = idx >> 7, k = idx & 127;
    WT[idx] = f2b(W[k * 128 + n]);
  }
}
__global__ void convert_wg(const float* __restrict__ Wg, unsigned short* __restrict__ WgT) {
  int idx = blockIdx.x * 256 + threadIdx.x;
  if (idx < 384 * 384) {
    int n = idx / 384, k = idx - n * 384;
    WgT[idx] = f2b(Wg[k * 384 + n]);
  }
}
__global__ void convert_wa(const float* __restrict__ Wa, unsigned short* __restrict__ WaT) {
  int idx = blockIdx.x * 256 + threadIdx.x;
  if (idx < 128 * 384) {
    int n = idx / 384, k = idx - n * 384;
    WaT[idx] = f2b(Wa[k * 128 + n]);
  }
}

// ---------------------------------------------------------------------------
// Linear: Hb(bf16) = X(fp32) @ W  via MFMA. 64 rows/block, 4 waves x 16 rows.
// ---------------------------------------------------------------------------
#define LM 64
__global__ __launch_bounds__(256) void linear_mfma(
    const float* __restrict__ X, const unsigned short* __restrict__ WT,
    unsigned short* __restrict__ Hb, int nrows) {
  __shared__ unsigned short Xs[LM][136];
  const int t = threadIdx.x;
  const int row0 = blockIdx.x * LM;

  for (int i = t * 4; i < LM * 128; i += 1024) {
    int n = i >> 7, j = i & 127;
    int r = row0 + n;
    float4 v = make_float4(0.f, 0.f, 0.f, 0.f);
    if (r < nrows) v = *(const float4*)&X[(size_t)r * 128 + j];
    Xs[n][j] = f2b(v.x);
    Xs[n][j + 1] = f2b(v.y);
    Xs[n][j + 2] = f2b(v.z);
    Xs[n][j + 3] = f2b(v.w);
  }
  __syncthreads();

  const int wv = t >> 6;
  const int ln = t & 63;
  const int lr = ln & 15;
  const int lq = ln >> 4;
  const int m0 = wv * 16;

  bf16x8 a[4];
#pragma unroll
  for (int ks = 0; ks < 4; ks++)
    a[ks] = *(const bf16x8*)&Xs[m0 + lr][ks * 32 + lq * 8];

#pragma unroll
  for (int np = 0; np < 4; np++) {
    const int n0 = np * 32;
    f32x4 acc0 = {0.f, 0.f, 0.f, 0.f};
    f32x4 acc1 = {0.f, 0.f, 0.f, 0.f};
    const unsigned short* B0 = &WT[(size_t)(n0 + lr) * 128 + lq * 8];
    const unsigned short* B1 = B0 + 16 * 128;
#pragma unroll
    for (int ks = 0; ks < 4; ks++) {
      bf16x8 b0 = *(const bf16x8*)(B0 + ks * 32);
      bf16x8 b1 = *(const bf16x8*)(B1 + ks * 32);
      acc0 = __builtin_amdgcn_mfma_f32_16x16x32_bf16(a[ks], b0, acc0, 0, 0, 0);
      acc1 = __builtin_amdgcn_mfma_f32_16x16x32_bf16(a[ks], b1, acc1, 0, 0, 0);
    }
#pragma unroll
    for (int r = 0; r < 4; r++) {
      int grow = row0 + m0 + lq * 4 + r;
      if (grow < nrows) {
        Hb[(size_t)grow * 128 + n0 + lr] = f2b(acc0[r]);
        Hb[(size_t)grow * 128 + n0 + 16 + lr] = f2b(acc1[r]);
      }
    }
  }
}

// ---------------------------------------------------------------------------
// Partition: 4096 edges/block -> LDS hist -> reserve slack ranges -> LDS-stage
// bucket-ordered -> coalesced flush of (enc, dst) into per-bucket slack region.
// ---------------------------------------------------------------------------
__global__ __launch_bounds__(256) void partition_kernel(
    const int* __restrict__ e1, const int* __restrict__ e2,
    int* __restrict__ bucketCursor, uint2* __restrict__ recs) {
  __shared__ int hist[256];
  __shared__ int scan_s[256];
  __shared__ int lstart[256];
  __shared__ int gbase[NBUCK];
  __shared__ int lcur[NBUCK];
  __shared__ uint2 buf[PCHUNK];  // 32 KB

  const int t = threadIdx.x;
  const long base = (long)blockIdx.x * PCHUNK;
  const int n = (int)min((long)PCHUNK, (long)ETOT - base);

  hist[t] = 0;
  __syncthreads();

  uint2 myrec[PCHUNK / 256];
  int myb[PCHUNK / 256];
  int cnt = 0;
#pragma unroll
  for (int k = 0; k < PCHUNK / 256; k++) {
    int idx = t + k * 256;
    if (idx < n) {
      long i = base + idx;
      int enc, dst;
      if (i < E1) {
        dst = e1[E1 + i];
        enc = N_V + e1[i];
      } else {
        long j = i - E1;
        dst = e2[E2 + j];
        enc = e2[j];
      }
      myrec[cnt] = make_uint2((unsigned)enc, (unsigned)dst);
      int b = dst >> 9;
      myb[cnt] = b;
      atomicAdd(&hist[b], 1);
      cnt++;
    }
  }
  __syncthreads();

  int v = hist[t];
  scan_s[t] = v;
  __syncthreads();
  for (int off = 1; off < 256; off <<= 1) {
    int tmp = (t >= off) ? scan_s[t - off] : 0;
    __syncthreads();
    scan_s[t] += tmp;
    __syncthreads();
  }
  lstart[t] = scan_s[t] - v;
  if (t < NBUCK) {
    gbase[t] = atomicAdd(&bucketCursor[t], v);
    lcur[t] = scan_s[t] - v;
  }
  __syncthreads();

  for (int k = 0; k < cnt; k++) {
    int p = atomicAdd(&lcur[myb[k]], 1);
    buf[p] = myrec[k];
  }
  __syncthreads();

  for (int p = t; p < n; p += 256) {
    uint2 r = buf[p];
    int b = (int)(r.y >> 9);
    recs[(size_t)b * SLACK + gbase[b] + (p - lstart[b])] = r;
  }
}

// Scan bucket counts -> compact bases.
__global__ __launch_bounds__(256) void bucket_scan(
    const int* __restrict__ bucketCnt, int* __restrict__ bucketBase) {
  __shared__ int s[256];
  const int t = threadIdx.x;
  int v = (t < NBUCK) ? bucketCnt[t] : 0;
  s[t] = v;
  __syncthreads();
  for (int off = 1; off < 256; off <<= 1) {
    int tmp = (t >= off) ? s[t - off] : 0;
    __syncthreads();
    s[t] += tmp;
    __syncthreads();
  }
  if (t < NBUCK) bucketBase[t] = s[t] - v;
  if (t == 255) bucketBase[NBUCK] = s[255];
}

// One block per bucket: per-node 16-category hist+scan -> row_ptr; each node's
// segment ordered by (relation, src-eighth): r2 slices 0..7 then r1 slices
// 0..7. Concurrently-running aggregate blocks walk categories in the same
// order, so the instantaneous gather working set is one 12.5K-row slice
// (3.2 MB < 4 MiB per-XCD L2) instead of a 25.6 MB half-table.
// col holds BYTE offsets into Hb (enc*256).
__global__ __launch_bounds__(512) void bucket_fill(
    const uint2* __restrict__ recs, const int* __restrict__ bucketCnt,
    const int* __restrict__ bucketBase, int* __restrict__ row_ptr,
    int* __restrict__ col) {
  __shared__ int hist[512 * NCAT];  // 32 KB
  __shared__ int cur[512 * NCAT];   // 32 KB
  __shared__ int s[512];
  const int t = threadIdx.x;
  const int b = blockIdx.x;
  const size_t slack = (size_t)b * SLACK;
  const int n = bucketCnt[b];
  const int outBase = bucketBase[b];
  const int n0 = b << 9;

#pragma unroll
  for (int c = 0; c < NCAT; c++) hist[t * NCAT + c] = 0;
  __syncthreads();
  for (int p = t; p < n; p += 512) {
    uint2 r = recs[slack + p];
    int local = (int)r.y - n0;
    unsigned enc = r.x;
    int cat = (enc >= (unsigned)N_V) ? (8 + (int)((enc - N_V) / SRCW))
                                     : (int)(enc / SRCW);
    atomicAdd(&hist[local * NCAT + cat], 1);
  }
  __syncthreads();

  int c[NCAT];
  int v = 0;
#pragma unroll
  for (int q = 0; q < NCAT; q++) { c[q] = hist[t * NCAT + q]; v += c[q]; }
  s[t] = v;
  __syncthreads();
  for (int off = 1; off < 512; off <<= 1) {
    int tmp = (t >= off) ? s[t - off] : 0;
    __syncthreads();
    s[t] += tmp;
    __syncthreads();
  }
  int run = s[t] - v;
  int excl = run;
#pragma unroll
  for (int q = 0; q < NCAT; q++) { cur[t * NCAT + q] = run; run += c[q]; }
  int nd = n0 + t;
  if (nd < N_V) row_ptr[nd] = outBase + excl;
  if (b == 0 && t == 0) row_ptr[N_V] = ETOT;
  __syncthreads();

  for (int p = t; p < n; p += 512) {
    uint2 r = recs[slack + p];
    int local = (int)r.y - n0;
    unsigned enc = r.x;
    int cat = (enc >= (unsigned)N_V) ? (8 + (int)((enc - N_V) / SRCW))
                                     : (int)(enc / SRCW);
    int q = atomicAdd(&cur[local * NCAT + cat], 1);
    col[outBase + q] = (int)(enc << 8);  // byte offset of Hb row
  }
}

// ---------------------------------------------------------------------------
// Aggregation v2 (round-2 version, full-row reads): one wave per dst node,
// 4 edges per wave-instruction. Lane l reads uint4 (8 bf16 feats) of edge
// (i + (l>>4)) at feat slot (l&15); 64 lanes cover 4 full 256B rows (100%
// line utilization). Butterfly shfl_xor(16,32) combines the 4 edge-groups;
// lanes 0-15 write Sum, 16-31 Max. Tail edges masked to zero (neutral).
// L2 locality comes from bucket_fill's 16-category segment ordering.
// ---------------------------------------------------------------------------
#define AGG1(w)                                        \
  do {                                                 \
    float lo = b2f_lo(w), hi = b2f_hi(w);              \
    s[2 * q] += lo; s[2 * q + 1] += hi;                \
    m[2 * q] = fmaxf(m[2 * q], lo);                    \
    m[2 * q + 1] = fmaxf(m[2 * q + 1], hi);            \
  } while (0)

__global__ __launch_bounds__(256) void aggregate_kernel(
    const unsigned short* __restrict__ Hb, const int* __restrict__ row_ptr,
    const int* __restrict__ col, unsigned int* __restrict__ SumB,
    unsigned int* __restrict__ MxB) {
  const int node = blockIdx.x * 4 + (threadIdx.x >> 6);
  const int lane = threadIdx.x & 63;
  const int grp = lane >> 4;   // which edge within group-of-4
  const int fl = lane & 15;    // feat slot: feats 8*fl .. 8*fl+7
  const int start = row_ptr[node];
  const int end = row_ptr[node + 1];
  const char* Hc = (const char*)Hb;
  const int byteoff = fl * 16;

  float s[8] = {0.f, 0.f, 0.f, 0.f, 0.f, 0.f, 0.f, 0.f};
  float m[8] = {0.f, 0.f, 0.f, 0.f, 0.f, 0.f, 0.f, 0.f};

  int i = start;
  for (; i + 31 < end; i += 32) {
    uint4 v[8];
#pragma unroll
    for (int g = 0; g < 8; g++) {
      int e = i + g * 4 + grp;
      v[g] = *(const uint4*)(Hc + (unsigned)col[e] + byteoff);
    }
#pragma unroll
    for (int g = 0; g < 8; g++) {
      { int q = 0; AGG1(v[g].x); }
      { int q = 1; AGG1(v[g].y); }
      { int q = 2; AGG1(v[g].z); }
      { int q = 3; AGG1(v[g].w); }
    }
  }
  for (; i < end; i += 4) {
    int e = i + grp;
    int ec = e < end ? e : (end - 1);
    uint4 v = *(const uint4*)(Hc + (unsigned)col[ec] + byteoff);
    if (e >= end) { v.x = 0u; v.y = 0u; v.z = 0u; v.w = 0u; }
    { int q = 0; AGG1(v.x); }
    { int q = 1; AGG1(v.y); }
    { int q = 2; AGG1(v.z); }
    { int q = 3; AGG1(v.w); }
  }

  // reduce across the 4 edge-groups (lanes l, l^16, l^32, l^48)
#pragma unroll
  for (int k = 0; k < 8; k++) {
    s[k] += __shfl_xor(s[k], 16, 64);
    m[k] = fmaxf(m[k], __shfl_xor(m[k], 16, 64));
    s[k] += __shfl_xor(s[k], 32, 64);
    m[k] = fmaxf(m[k], __shfl_xor(m[k], 32, 64));
  }

  if (lane < 16) {
    uint4 o;
    o.x = (unsigned)f2b(s[0]) | ((unsigned)f2b(s[1]) << 16);
    o.y = (unsigned)f2b(s[2]) | ((unsigned)f2b(s[3]) << 16);
    o.z = (unsigned)f2b(s[4]) | ((unsigned)f2b(s[5]) << 16);
    o.w = (unsigned)f2b(s[6]) | ((unsigned)f2b(s[7]) << 16);
    ((uint4*)SumB)[(size_t)node * 16 + fl] = o;
  } else if (lane < 32) {
    uint4 o;
    o.x = (unsigned)f2b(m[0]) | ((unsigned)f2b(m[1]) << 16);
    o.y = (unsigned)f2b(m[2]) | ((unsigned)f2b(m[3]) << 16);
    o.z = (unsigned)f2b(m[4]) | ((unsigned)f2b(m[5]) << 16);
    o.w = (unsigned)f2b(m[6]) | ((unsigned)f2b(m[7]) << 16);
    ((uint4*)MxB)[(size_t)node * 16 + fl] = o;
  }
}

// ---------------------------------------------------------------------------
// MFMA epilogue v3 (round-2 version): no LDS B-panel. B-fragments load
// directly from L2-hot weight tables. Wave M-blocking: each wave computes all
// 64 rows x 96 gate cols -> 24 MFMA per 10 fragment loads, barrier-free
// k-loops with 2x unroll for load/MFMA overlap.
// ---------------------------------------------------------------------------
#define EM 64
__global__ __launch_bounds__(256, 3) void epilogue_mfma(
    const unsigned short* __restrict__ SumB, const unsigned short* __restrict__ MxB,
    const int* __restrict__ row_ptr, const unsigned short* __restrict__ Wg16,
    const float* __restrict__ bg, const unsigned short* __restrict__ Wa16,
    const float* __restrict__ ba, float* __restrict__ Out) {
  __shared__ unsigned short Ts[EM][392];   // 50176 B
  __shared__ float invs[EM];
  __shared__ int cnts[EM];

  const int t = threadIdx.x;
  const int node0 = blockIdx.x * EM;

  if (t < EM) {
    int nd = node0 + t;
    int c = 0;
    if (nd < N_V) c = row_ptr[nd + 1] - row_ptr[nd];
    cnts[t] = c;
    invs[t] = 1.0f / (float)(c > 0 ? c : 1);
  }
  __syncthreads();

  // Build Ts = [sum(128) | mean(128) | max(128)] bf16, 16B-vectorized.
  {
    const uint4* Sv = (const uint4*)SumB;
    const uint4* Mv = (const uint4*)MxB;
    for (int i = t; i < EM * 16; i += 256) {
      int n = i >> 4, u = i & 15;
      int nd = node0 + n;
      uint4 s = make_uint4(0u, 0u, 0u, 0u);
      uint4 m4 = make_uint4(0u, 0u, 0u, 0u);
      if (nd < N_V) {
        s = Sv[(size_t)nd * 16 + u];
        m4 = Mv[(size_t)nd * 16 + u];
      }
      float inv = invs[n];
      *(uint4*)&Ts[n][u * 8] = s;
      unsigned sw[4] = {s.x, s.y, s.z, s.w};
      unsigned mr[4];
#pragma unroll
      for (int q = 0; q < 4; q++) {
        unsigned short lo = f2b(b2f((unsigned short)sw[q]) * inv);
        unsigned short hi = f2b(b2f((unsigned short)(sw[q] >> 16)) * inv);
        mr[q] = (unsigned)lo | ((unsigned)hi << 16);
      }
      *(uint4*)&Ts[n][128 + u * 8] = make_uint4(mr[0], mr[1], mr[2], mr[3]);
      *(uint4*)&Ts[n][256 + u * 8] = m4;
    }
  }
  __syncthreads();

  const int wv = t >> 6;
  const int ln = t & 63;
  const int lr = ln & 15;
  const int lq = ln >> 4;

  // ---- Gate GEMM: acc[m][nt], rows m*16+lq*4+r, cols wv*96+nt*16+lr ----
  f32x4 acc[4][6];
#pragma unroll
  for (int m = 0; m < 4; m++)
#pragma unroll
    for (int nt = 0; nt < 6; nt++) acc[m][nt] = (f32x4){0.f, 0.f, 0.f, 0.f};

  const unsigned short* Bg = Wg16 + (size_t)(wv * 96 + lr) * 384 + lq * 8;

#pragma unroll 2
  for (int kc = 0; kc < 12; kc++) {
    bf16x8 b[6];
#pragma unroll
    for (int nt = 0; nt < 6; nt++)
      b[nt] = *(const bf16x8*)(Bg + nt * (16 * 384) + kc * 32);
    bf16x8 a[4];
#pragma unroll
    for (int m = 0; m < 4; m++)
      a[m] = *(const bf16x8*)&Ts[m * 16 + lr][kc * 32 + lq * 8];
#pragma unroll
    for (int m = 0; m < 4; m++)
#pragma unroll
      for (int nt = 0; nt < 6; nt++)
        acc[m][nt] = __builtin_amdgcn_mfma_f32_16x16x32_bf16(a[m], b[nt], acc[m][nt], 0, 0, 0);
  }
  __syncthreads();  // all Ts reads done before gated rewrite

  // Gate apply: wave wv owns cols [wv*96, wv*96+96), all 64 rows.
#pragma unroll
  for (int nt = 0; nt < 6; nt++) {
    int cg = wv * 96 + nt * 16 + lr;
    float bgv = bg[cg];
#pragma unroll
    for (int m = 0; m < 4; m++) {
#pragma unroll
      for (int r = 0; r < 4; r++) {
        int row = m * 16 + lq * 4 + r;
        float g = 1.f / (1.f + __expf(-(acc[m][nt][r] + bgv)));
        Ts[row][cg] = f2b(b2f(Ts[row][cg]) * g);
      }
    }
  }
  __syncthreads();  // gated Ts ready for aggr GEMM

  // ---- Aggr GEMM: acc2[m][nt], cols wv*32+nt*16+lr ----
  f32x4 acc2[4][2];
#pragma unroll
  for (int m = 0; m < 4; m++)
#pragma unroll
    for (int nt = 0; nt < 2; nt++) acc2[m][nt] = (f32x4){0.f, 0.f, 0.f, 0.f};

  const unsigned short* Ba = Wa16 + (size_t)(wv * 32 + lr) * 384 + lq * 8;

#pragma unroll 2
  for (int kc = 0; kc < 12; kc++) {
    bf16x8 b[2];
#pragma unroll
    for (int nt = 0; nt < 2; nt++)
      b[nt] = *(const bf16x8*)(Ba + nt * (16 * 384) + kc * 32);
    bf16x8 a[4];
#pragma unroll
    for (int m = 0; m < 4; m++)
      a[m] = *(const bf16x8*)&Ts[m * 16 + lr][kc * 32 + lq * 8];
#pragma unroll
    for (int m = 0; m < 4; m++)
#pragma unroll
      for (int nt = 0; nt < 2; nt++)
        acc2[m][nt] = __builtin_amdgcn_mfma_f32_16x16x32_bf16(a[m], b[nt], acc2[m][nt], 0, 0, 0);
  }

#pragma unroll
  for (int nt = 0; nt < 2; nt++) {
    int cg = wv * 32 + nt * 16 + lr;
    float bav = ba[cg];
#pragma unroll
    for (int m = 0; m < 4; m++) {
#pragma unroll
      for (int r = 0; r < 4; r++) {
        int row = m * 16 + lq * 4 + r;
        int nd = node0 + row;
        if (nd < N_V) {
          float msk = (cnts[row] > 0) ? 1.f : 0.f;
          Out[(size_t)nd * D + cg] = (acc2[m][nt][r] + bav) * msk;
        }
      }
    }
  }
}

// ---------------------------------------------------------------------------
extern "C" void kernel_launch(void* const* d_in, const int* in_sizes, int n_in,
                              void* d_out, int out_size, void* d_ws, size_t ws_size,
                              hipStream_t stream) {
  const float* x_u = (const float*)d_in[0];
  const float* x_v = (const float*)d_in[1];
  const float* W_r1 = (const float*)d_in[2];
  const float* W_r2 = (const float*)d_in[3];
  const float* W_gate = (const float*)d_in[4];
  const float* b_gate = (const float*)d_in[5];
  const float* W_aggr = (const float*)d_in[6];
  const float* b_aggr = (const float*)d_in[7];
  const int* e1 = (const int*)d_in[8];
  const int* e2 = (const int*)d_in[9];
  float* out = (float*)d_out;

  char* ws = (char*)d_ws;
  size_t off = 0;
  unsigned short* Hb = (unsigned short*)(ws + off); off += (size_t)(N_V + N_U) * D * 2;
  unsigned int* SumB = (unsigned int*)(ws + off);   off += (size_t)N_V * D * 2;
  unsigned int* MxB = (unsigned int*)(ws + off);    off += (size_t)N_V * D * 2;
  int* colA = (int*)(ws + off);        off += (size_t)ETOT * 4;
  uint2* recs = (uint2*)(ws + off);    off += (size_t)NBUCK * SLACK * 8;
  int* row_ptr = (int*)(ws + off);     off += (size_t)(N_V + 1) * 4;
  int* bucketCursor = (int*)(ws + off); off += NBUCK * 4;
  int* bucketBase = (int*)(ws + off);  off += (NBUCK + 1) * 4;
  unsigned short* Wg16 = (unsigned short*)(ws + off); off += (size_t)384 * 384 * 2;
  unsigned short* Wa16 = (unsigned short*)(ws + off); off += (size_t)128 * 384 * 2;
  unsigned short* Wr1T = (unsigned short*)(ws + off); off += (size_t)128 * 128 * 2;
  unsigned short* Wr2T = (unsigned short*)(ws + off); off += (size_t)128 * 128 * 2;

  hipMemsetAsync(bucketCursor, 0, NBUCK * 4, stream);

  convert_w128<<<64, 256, 0, stream>>>(W_r1, Wr1T);
  convert_w128<<<64, 256, 0, stream>>>(W_r2, Wr2T);
  convert_wg<<<(384 * 384 + 255) / 256, 256, 0, stream>>>(W_gate, Wg16);
  convert_wa<<<(128 * 384 + 255) / 256, 256, 0, stream>>>(W_aggr, Wa16);

  linear_mfma<<<(N_V + LM - 1) / LM, 256, 0, stream>>>(x_v, Wr2T, Hb, N_V);
  linear_mfma<<<(N_U + LM - 1) / LM, 256, 0, stream>>>(x_u, Wr1T, Hb + (size_t)N_V * D, N_U);

  partition_kernel<<<(ETOT + PCHUNK - 1) / PCHUNK, 256, 0, stream>>>(
      e1, e2, bucketCursor, recs);
  bucket_scan<<<1, 256, 0, stream>>>(bucketCursor, bucketBase);
  bucket_fill<<<NBUCK, 512, 0, stream>>>(recs, bucketCursor, bucketBase, row_ptr, colA);

  aggregate_kernel<<<N_V / 4, 256, 0, stream>>>(Hb, row_ptr, colA, SumB, MxB);

  epilogue_mfma<<<(N_V + EM - 1) / EM, 256, 0, stream>>>(
      (const unsigned short*)SumB, (const unsigned short*)MxB, row_ptr,
      Wg16, b_gate, Wa16, b_aggr, out);
}

// Round 6
// 657.812 us; speedup vs baseline: 1.4787x; 1.1246x over previous
//
#include <hip/hip_runtime.h>
#include <math.h>

#define N_U 100000
#define N_V 100000
#define D 128
#define E1 3200000
#define E2 3200000
#define ETOT (E1 + E2)

#define NBUCK 196      // buckets of 512 dst nodes: dst >> 9
#define SLACK 35000    // per-bucket record capacity (expected 32768 +/- ~180)
#define PCHUNK 4096    // edges per partition block

typedef __bf16 bf16x8 __attribute__((ext_vector_type(8)));
typedef float f32x4 __attribute__((ext_vector_type(4)));

__device__ __forceinline__ unsigned short f2b(float f) {
  union { float f; unsigned int u; } v; v.f = f;
  unsigned int u = v.u;
  unsigned int r = u + 0x7fffu + ((u >> 16) & 1u);
  return (unsigned short)(r >> 16);
}
__device__ __forceinline__ float b2f(unsigned short s) {
  union { unsigned int u; float f; } v; v.u = ((unsigned int)s) << 16; return v.f;
}
// packed-bf16 dword -> two floats (2 VALU ops total)
__device__ __forceinline__ float b2f_lo(unsigned w) {
  union { unsigned u; float f; } v; v.u = w << 16; return v.f;
}
__device__ __forceinline__ float b2f_hi(unsigned w) {
  union { unsigned u; float f; } v; v.u = w & 0xffff0000u; return v.f;
}

// ---------------------------------------------------------------------------
// Weight convert: MFMA-fragment-packed bf16 layout. For B-operand of
// mfma_f32_16x16x32_bf16, lane (lr,lq) holds B[k=kc*32+lq*8+e][col=n0+lr].
// Packed index: frag = (n>>4)*KG + (k>>5); idx = frag*512 +
// ((n&15) + 16*((k>>3)&3))*8 + (k&7).  One fragment = 1KB contiguous ->
// every wave B-load is a single coalesced 1KB burst (8 lines, 0 split).
// ---------------------------------------------------------------------------
__global__ void convert_w128(const float* __restrict__ W, unsigned short* __restrict__ WF) {
  int idx = blockIdx.x * 256 + threadIdx.x;
  if (idx < 128 * 128) {
    int k = idx >> 7, n = idx & 127;
    int f = (n >> 4) * 4 + (k >> 5);
    int out = f * 512 + ((n & 15) + 16 * ((k >> 3) & 3)) * 8 + (k & 7);
    WF[out] = f2b(W[k * 128 + n]);
  }
}
__global__ void convert_wg(const float* __restrict__ Wg, unsigned short* __restrict__ WgF) {
  int idx = blockIdx.x * 256 + threadIdx.x;
  if (idx < 384 * 384) {
    int k = idx / 384, n = idx - k * 384;
    int f = (n >> 4) * 12 + (k >> 5);
    int out = f * 512 + ((n & 15) + 16 * ((k >> 3) & 3)) * 8 + (k & 7);
    WgF[out] = f2b(Wg[k * 384 + n]);
  }
}
__global__ void convert_wa(const float* __restrict__ Wa, unsigned short* __restrict__ WaF) {
  int idx = blockIdx.x * 256 + threadIdx.x;
  if (idx < 384 * 128) {
    int k = idx >> 7, n = idx & 127;
    int f = (n >> 4) * 12 + (k >> 5);
    int out = f * 512 + ((n & 15) + 16 * ((k >> 3) & 3)) * 8 + (k & 7);
    WaF[out] = f2b(Wa[k * 128 + n]);
  }
}

// ---------------------------------------------------------------------------
// Linear: Hb(bf16) = X(fp32) @ W  via MFMA. 64 rows/block, 4 waves x 16 rows.
// B-fragments from fragment-packed WF: coalesced 1KB wave-loads.
// ---------------------------------------------------------------------------
#define LM 64
__global__ __launch_bounds__(256) void linear_mfma(
    const float* __restrict__ X, const unsigned short* __restrict__ WF,
    unsigned short* __restrict__ Hb, int nrows) {
  __shared__ unsigned short Xs[LM][136];
  const int t = threadIdx.x;
  const int row0 = blockIdx.x * LM;

  for (int i = t * 4; i < LM * 128; i += 1024) {
    int n = i >> 7, j = i & 127;
    int r = row0 + n;
    float4 v = make_float4(0.f, 0.f, 0.f, 0.f);
    if (r < nrows) v = *(const float4*)&X[(size_t)r * 128 + j];
    Xs[n][j] = f2b(v.x);
    Xs[n][j + 1] = f2b(v.y);
    Xs[n][j + 2] = f2b(v.z);
    Xs[n][j + 3] = f2b(v.w);
  }
  __syncthreads();

  const int wv = t >> 6;
  const int ln = t & 63;
  const int lr = ln & 15;
  const int lq = ln >> 4;
  const int m0 = wv * 16;

  bf16x8 a[4];
#pragma unroll
  for (int ks = 0; ks < 4; ks++)
    a[ks] = *(const bf16x8*)&Xs[m0 + lr][ks * 32 + lq * 8];

#pragma unroll
  for (int np = 0; np < 4; np++) {
    const int n0 = np * 32;
    f32x4 acc0 = {0.f, 0.f, 0.f, 0.f};
    f32x4 acc1 = {0.f, 0.f, 0.f, 0.f};
    // col-groups g0 = np*2, g1 = np*2+1; frag(g,ks) at (g*4+ks)*512 + ln*8
    const unsigned short* B0 = WF + (size_t)(np * 2) * 4 * 512 + ln * 8;
    const unsigned short* B1 = B0 + 4 * 512;
#pragma unroll
    for (int ks = 0; ks < 4; ks++) {
      bf16x8 b0 = *(const bf16x8*)(B0 + ks * 512);
      bf16x8 b1 = *(const bf16x8*)(B1 + ks * 512);
      acc0 = __builtin_amdgcn_mfma_f32_16x16x32_bf16(a[ks], b0, acc0, 0, 0, 0);
      acc1 = __builtin_amdgcn_mfma_f32_16x16x32_bf16(a[ks], b1, acc1, 0, 0, 0);
    }
#pragma unroll
    for (int r = 0; r < 4; r++) {
      int grow = row0 + m0 + lq * 4 + r;
      if (grow < nrows) {
        Hb[(size_t)grow * 128 + n0 + lr] = f2b(acc0[r]);
        Hb[(size_t)grow * 128 + n0 + 16 + lr] = f2b(acc1[r]);
      }
    }
  }
}

// ---------------------------------------------------------------------------
// Partition: 4096 edges/block -> LDS hist -> reserve slack ranges -> LDS-stage
// bucket-ordered -> coalesced flush of (enc, dst) into per-bucket slack region.
// ---------------------------------------------------------------------------
__global__ __launch_bounds__(256) void partition_kernel(
    const int* __restrict__ e1, const int* __restrict__ e2,
    int* __restrict__ bucketCursor, uint2* __restrict__ recs) {
  __shared__ int hist[256];
  __shared__ int scan_s[256];
  __shared__ int lstart[256];
  __shared__ int gbase[NBUCK];
  __shared__ int lcur[NBUCK];
  __shared__ uint2 buf[PCHUNK];  // 32 KB

  const int t = threadIdx.x;
  const long base = (long)blockIdx.x * PCHUNK;
  const int n = (int)min((long)PCHUNK, (long)ETOT - base);

  hist[t] = 0;
  __syncthreads();

  uint2 myrec[PCHUNK / 256];
  int myb[PCHUNK / 256];
  int cnt = 0;
#pragma unroll
  for (int k = 0; k < PCHUNK / 256; k++) {
    int idx = t + k * 256;
    if (idx < n) {
      long i = base + idx;
      int enc, dst;
      if (i < E1) {
        dst = e1[E1 + i];
        enc = N_V + e1[i];
      } else {
        long j = i - E1;
        dst = e2[E2 + j];
        enc = e2[j];
      }
      myrec[cnt] = make_uint2((unsigned)enc, (unsigned)dst);
      int b = dst >> 9;
      myb[cnt] = b;
      atomicAdd(&hist[b], 1);
      cnt++;
    }
  }
  __syncthreads();

  int v = hist[t];
  scan_s[t] = v;
  __syncthreads();
  for (int off = 1; off < 256; off <<= 1) {
    int tmp = (t >= off) ? scan_s[t - off] : 0;
    __syncthreads();
    scan_s[t] += tmp;
    __syncthreads();
  }
  lstart[t] = scan_s[t] - v;
  if (t < NBUCK) {
    gbase[t] = atomicAdd(&bucketCursor[t], v);
    lcur[t] = scan_s[t] - v;
  }
  __syncthreads();

  for (int k = 0; k < cnt; k++) {
    int p = atomicAdd(&lcur[myb[k]], 1);
    buf[p] = myrec[k];
  }
  __syncthreads();

  for (int p = t; p < n; p += 256) {
    uint2 r = buf[p];
    int b = (int)(r.y >> 9);
    recs[(size_t)b * SLACK + gbase[b] + (p - lstart[b])] = r;
  }
}

// Scan bucket counts -> compact bases.
__global__ __launch_bounds__(256) void bucket_scan(
    const int* __restrict__ bucketCnt, int* __restrict__ bucketBase) {
  __shared__ int s[256];
  const int t = threadIdx.x;
  int v = (t < NBUCK) ? bucketCnt[t] : 0;
  s[t] = v;
  __syncthreads();
  for (int off = 1; off < 256; off <<= 1) {
    int tmp = (t >= off) ? s[t - off] : 0;
    __syncthreads();
    s[t] += tmp;
    __syncthreads();
  }
  if (t < NBUCK) bucketBase[t] = s[t] - v;
  if (t == 255) bucketBase[NBUCK] = s[255];
}

// One block per bucket: per-node hist+scan -> row_ptr; two-ended fill so each
// node's segment is [r2 edges ... r1 edges].
// col holds BYTE offsets into Hb (enc*256).
__global__ __launch_bounds__(512) void bucket_fill(
    const uint2* __restrict__ recs, const int* __restrict__ bucketCnt,
    const int* __restrict__ bucketBase, int* __restrict__ row_ptr,
    int* __restrict__ col) {
  __shared__ int hist[512];
  __shared__ int s[512];
  __shared__ int curF[512];
  __shared__ int curB[512];
  const int t = threadIdx.x;
  const int b = blockIdx.x;
  const size_t slack = (size_t)b * SLACK;
  const int n = bucketCnt[b];
  const int outBase = bucketBase[b];
  const int n0 = b << 9;

  hist[t] = 0;
  __syncthreads();
  for (int p = t; p < n; p += 512)
    atomicAdd(&hist[recs[slack + p].y - n0], 1);
  __syncthreads();

  int v = hist[t];
  s[t] = v;
  __syncthreads();
  for (int off = 1; off < 512; off <<= 1) {
    int tmp = (t >= off) ? s[t - off] : 0;
    __syncthreads();
    s[t] += tmp;
    __syncthreads();
  }
  int excl = s[t] - v;
  curF[t] = excl;       // front cursor: r2 edges (enc < N_V)
  curB[t] = excl + v;   // back cursor: r1 edges (enc >= N_V)
  int nd = n0 + t;
  if (nd < N_V) row_ptr[nd] = outBase + excl;
  if (b == 0 && t == 0) row_ptr[N_V] = ETOT;
  __syncthreads();

  for (int p = t; p < n; p += 512) {
    uint2 r = recs[slack + p];
    int local = r.y - n0;
    int q;
    if (r.x >= (unsigned)N_V) q = atomicSub(&curB[local], 1) - 1;
    else q = atomicAdd(&curF[local], 1);
    col[outBase + q] = (int)(r.x << 8);  // byte offset of Hb row
  }
}

// ---------------------------------------------------------------------------
// Aggregation v2: one wave per dst node, 4 edges per wave-instruction.
// Lane l reads uint4 (8 bf16 feats) of edge (i + (l>>4)) at feat slot (l&15);
// 64 lanes cover 4 full 256B rows (100% line utilization). Butterfly
// shfl_xor(16,32) combines the 4 edge-groups; lanes 0-15 write Sum, 16-31 Max.
// ---------------------------------------------------------------------------
#define AGG1(w)                                        \
  do {                                                 \
    float lo = b2f_lo(w), hi = b2f_hi(w);              \
    s[2 * q] += lo; s[2 * q + 1] += hi;                \
    m[2 * q] = fmaxf(m[2 * q], lo);                    \
    m[2 * q + 1] = fmaxf(m[2 * q + 1], hi);            \
  } while (0)

__global__ __launch_bounds__(256) void aggregate_kernel(
    const unsigned short* __restrict__ Hb, const int* __restrict__ row_ptr,
    const int* __restrict__ col, unsigned int* __restrict__ SumB,
    unsigned int* __restrict__ MxB) {
  const int node = blockIdx.x * 4 + (threadIdx.x >> 6);
  const int lane = threadIdx.x & 63;
  const int grp = lane >> 4;   // which edge within group-of-4
  const int fl = lane & 15;    // feat slot: feats 8*fl .. 8*fl+7
  const int start = row_ptr[node];
  const int end = row_ptr[node + 1];
  const char* Hc = (const char*)Hb;
  const int byteoff = fl * 16;

  float s[8] = {0.f, 0.f, 0.f, 0.f, 0.f, 0.f, 0.f, 0.f};
  float m[8] = {0.f, 0.f, 0.f, 0.f, 0.f, 0.f, 0.f, 0.f};

  int i = start;
  for (; i + 31 < end; i += 32) {
    uint4 v[8];
#pragma unroll
    for (int g = 0; g < 8; g++) {
      int e = i + g * 4 + grp;
      v[g] = *(const uint4*)(Hc + (unsigned)col[e] + byteoff);
    }
#pragma unroll
    for (int g = 0; g < 8; g++) {
      { int q = 0; AGG1(v[g].x); }
      { int q = 1; AGG1(v[g].y); }
      { int q = 2; AGG1(v[g].z); }
      { int q = 3; AGG1(v[g].w); }
    }
  }
  for (; i < end; i += 4) {
    int e = i + grp;
    int ec = e < end ? e : (end - 1);
    uint4 v = *(const uint4*)(Hc + (unsigned)col[ec] + byteoff);
    if (e >= end) { v.x = 0u; v.y = 0u; v.z = 0u; v.w = 0u; }
    { int q = 0; AGG1(v.x); }
    { int q = 1; AGG1(v.y); }
    { int q = 2; AGG1(v.z); }
    { int q = 3; AGG1(v.w); }
  }

  // reduce across the 4 edge-groups (lanes l, l^16, l^32, l^48)
#pragma unroll
  for (int k = 0; k < 8; k++) {
    s[k] += __shfl_xor(s[k], 16, 64);
    m[k] = fmaxf(m[k], __shfl_xor(m[k], 16, 64));
    s[k] += __shfl_xor(s[k], 32, 64);
    m[k] = fmaxf(m[k], __shfl_xor(m[k], 32, 64));
  }

  if (lane < 16) {
    uint4 o;
    o.x = (unsigned)f2b(s[0]) | ((unsigned)f2b(s[1]) << 16);
    o.y = (unsigned)f2b(s[2]) | ((unsigned)f2b(s[3]) << 16);
    o.z = (unsigned)f2b(s[4]) | ((unsigned)f2b(s[5]) << 16);
    o.w = (unsigned)f2b(s[6]) | ((unsigned)f2b(s[7]) << 16);
    ((uint4*)SumB)[(size_t)node * 16 + fl] = o;
  } else if (lane < 32) {
    uint4 o;
    o.x = (unsigned)f2b(m[0]) | ((unsigned)f2b(m[1]) << 16);
    o.y = (unsigned)f2b(m[2]) | ((unsigned)f2b(m[3]) << 16);
    o.z = (unsigned)f2b(m[4]) | ((unsigned)f2b(m[5]) << 16);
    o.w = (unsigned)f2b(m[6]) | ((unsigned)f2b(m[7]) << 16);
    ((uint4*)MxB)[(size_t)node * 16 + fl] = o;
  }
}

// ---------------------------------------------------------------------------
// MFMA epilogue v5: B-fragments from fragment-packed weight tables -> every
// wave B-load is one coalesced 1KB burst (was 16-way line-split). Barrier-free
// k-loops, wave M-blocking (all 64 rows x 96/32 cols per wave).
// ---------------------------------------------------------------------------
#define EM 64
__global__ __launch_bounds__(256, 3) void epilogue_mfma(
    const unsigned short* __restrict__ SumB, const unsigned short* __restrict__ MxB,
    const int* __restrict__ row_ptr, const unsigned short* __restrict__ WgF,
    const float* __restrict__ bg, const unsigned short* __restrict__ WaF,
    const float* __restrict__ ba, float* __restrict__ Out) {
  __shared__ unsigned short Ts[EM][392];   // 50176 B
  __shared__ float invs[EM];
  __shared__ int cnts[EM];

  const int t = threadIdx.x;
  const int node0 = blockIdx.x * EM;

  if (t < EM) {
    int nd = node0 + t;
    int c = 0;
    if (nd < N_V) c = row_ptr[nd + 1] - row_ptr[nd];
    cnts[t] = c;
    invs[t] = 1.0f / (float)(c > 0 ? c : 1);
  }
  __syncthreads();

  // Build Ts = [sum(128) | mean(128) | max(128)] bf16, 16B-vectorized.
  {
    const uint4* Sv = (const uint4*)SumB;
    const uint4* Mv = (const uint4*)MxB;
    for (int i = t; i < EM * 16; i += 256) {
      int n = i >> 4, u = i & 15;
      int nd = node0 + n;
      uint4 s = make_uint4(0u, 0u, 0u, 0u);
      uint4 m4 = make_uint4(0u, 0u, 0u, 0u);
      if (nd < N_V) {
        s = Sv[(size_t)nd * 16 + u];
        m4 = Mv[(size_t)nd * 16 + u];
      }
      float inv = invs[n];
      *(uint4*)&Ts[n][u * 8] = s;
      unsigned sw[4] = {s.x, s.y, s.z, s.w};
      unsigned mr[4];
#pragma unroll
      for (int q = 0; q < 4; q++) {
        unsigned short lo = f2b(b2f((unsigned short)sw[q]) * inv);
        unsigned short hi = f2b(b2f((unsigned short)(sw[q] >> 16)) * inv);
        mr[q] = (unsigned)lo | ((unsigned)hi << 16);
      }
      *(uint4*)&Ts[n][128 + u * 8] = make_uint4(mr[0], mr[1], mr[2], mr[3]);
      *(uint4*)&Ts[n][256 + u * 8] = m4;
    }
  }
  __syncthreads();

  const int wv = t >> 6;
  const int ln = t & 63;
  const int lr = ln & 15;
  const int lq = ln >> 4;

  // ---- Gate GEMM: acc[m][nt], rows m*16+lq*4+r, cols wv*96+nt*16+lr ----
  f32x4 acc[4][6];
#pragma unroll
  for (int m = 0; m < 4; m++)
#pragma unroll
    for (int nt = 0; nt < 6; nt++) acc[m][nt] = (f32x4){0.f, 0.f, 0.f, 0.f};

  // col-group for (wv,nt) = wv*6+nt; frag(g,kc) at (g*12+kc)*512 + ln*8
  const unsigned short* Bg = WgF + (size_t)(wv * 6) * 12 * 512 + ln * 8;

#pragma unroll 2
  for (int kc = 0; kc < 12; kc++) {
    bf16x8 b[6];
#pragma unroll
    for (int nt = 0; nt < 6; nt++)
      b[nt] = *(const bf16x8*)(Bg + (nt * 12 + kc) * 512);
    bf16x8 a[4];
#pragma unroll
    for (int m = 0; m < 4; m++)
      a[m] = *(const bf16x8*)&Ts[m * 16 + lr][kc * 32 + lq * 8];
#pragma unroll
    for (int m = 0; m < 4; m++)
#pragma unroll
      for (int nt = 0; nt < 6; nt++)
        acc[m][nt] = __builtin_amdgcn_mfma_f32_16x16x32_bf16(a[m], b[nt], acc[m][nt], 0, 0, 0);
  }
  __syncthreads();  // all Ts reads done before gated rewrite

  // Gate apply: wave wv owns cols [wv*96, wv*96+96), all 64 rows.
#pragma unroll
  for (int nt = 0; nt < 6; nt++) {
    int cg = wv * 96 + nt * 16 + lr;
    float bgv = bg[cg];
#pragma unroll
    for (int m = 0; m < 4; m++) {
#pragma unroll
      for (int r = 0; r < 4; r++) {
        int row = m * 16 + lq * 4 + r;
        float g = 1.f / (1.f + __expf(-(acc[m][nt][r] + bgv)));
        Ts[row][cg] = f2b(b2f(Ts[row][cg]) * g);
      }
    }
  }
  __syncthreads();  // gated Ts ready for aggr GEMM

  // ---- Aggr GEMM: acc2[m][nt], cols wv*32+nt*16+lr ----
  f32x4 acc2[4][2];
#pragma unroll
  for (int m = 0; m < 4; m++)
#pragma unroll
    for (int nt = 0; nt < 2; nt++) acc2[m][nt] = (f32x4){0.f, 0.f, 0.f, 0.f};

  const unsigned short* Ba = WaF + (size_t)(wv * 2) * 12 * 512 + ln * 8;

#pragma unroll 2
  for (int kc = 0; kc < 12; kc++) {
    bf16x8 b[2];
#pragma unroll
    for (int nt = 0; nt < 2; nt++)
      b[nt] = *(const bf16x8*)(Ba + (nt * 12 + kc) * 512);
    bf16x8 a[4];
#pragma unroll
    for (int m = 0; m < 4; m++)
      a[m] = *(const bf16x8*)&Ts[m * 16 + lr][kc * 32 + lq * 8];
#pragma unroll
    for (int m = 0; m < 4; m++)
#pragma unroll
      for (int nt = 0; nt < 2; nt++)
        acc2[m][nt] = __builtin_amdgcn_mfma_f32_16x16x32_bf16(a[m], b[nt], acc2[m][nt], 0, 0, 0);
  }

#pragma unroll
  for (int nt = 0; nt < 2; nt++) {
    int cg = wv * 32 + nt * 16 + lr;
    float bav = ba[cg];
#pragma unroll
    for (int m = 0; m < 4; m++) {
#pragma unroll
      for (int r = 0; r < 4; r++) {
        int row = m * 16 + lq * 4 + r;
        int nd = node0 + row;
        if (nd < N_V) {
          float msk = (cnts[row] > 0) ? 1.f : 0.f;
          Out[(size_t)nd * D + cg] = (acc2[m][nt][r] + bav) * msk;
        }
      }
    }
  }
}

// ---------------------------------------------------------------------------
extern "C" void kernel_launch(void* const* d_in, const int* in_sizes, int n_in,
                              void* d_out, int out_size, void* d_ws, size_t ws_size,
                              hipStream_t stream) {
  const float* x_u = (const float*)d_in[0];
  const float* x_v = (const float*)d_in[1];
  const float* W_r1 = (const float*)d_in[2];
  const float* W_r2 = (const float*)d_in[3];
  const float* W_gate = (const float*)d_in[4];
  const float* b_gate = (const float*)d_in[5];
  const float* W_aggr = (const float*)d_in[6];
  const float* b_aggr = (const float*)d_in[7];
  const int* e1 = (const int*)d_in[8];
  const int* e2 = (const int*)d_in[9];
  float* out = (float*)d_out;

  char* ws = (char*)d_ws;
  size_t off = 0;
  unsigned short* Hb = (unsigned short*)(ws + off); off += (size_t)(N_V + N_U) * D * 2;
  unsigned int* SumB = (unsigned int*)(ws + off);   off += (size_t)N_V * D * 2;
  unsigned int* MxB = (unsigned int*)(ws + off);    off += (size_t)N_V * D * 2;
  int* colA = (int*)(ws + off);        off += (size_t)ETOT * 4;
  uint2* recs = (uint2*)(ws + off);    off += (size_t)NBUCK * SLACK * 8;
  int* row_ptr = (int*)(ws + off);     off += (size_t)(N_V + 1) * 4;
  int* bucketCursor = (int*)(ws + off); off += NBUCK * 4;
  int* bucketBase = (int*)(ws + off);  off += (NBUCK + 1) * 4;
  unsigned short* Wg16 = (unsigned short*)(ws + off); off += (size_t)384 * 384 * 2;
  unsigned short* Wa16 = (unsigned short*)(ws + off); off += (size_t)128 * 384 * 2;
  unsigned short* Wr1T = (unsigned short*)(ws + off); off += (size_t)128 * 128 * 2;
  unsigned short* Wr2T = (unsigned short*)(ws + off); off += (size_t)128 * 128 * 2;

  hipMemsetAsync(bucketCursor, 0, NBUCK * 4, stream);

  convert_w128<<<64, 256, 0, stream>>>(W_r1, Wr1T);
  convert_w128<<<64, 256, 0, stream>>>(W_r2, Wr2T);
  convert_wg<<<(384 * 384 + 255) / 256, 256, 0, stream>>>(W_gate, Wg16);
  convert_wa<<<(128 * 384 + 255) / 256, 256, 0, stream>>>(W_aggr, Wa16);

  linear_mfma<<<(N_V + LM - 1) / LM, 256, 0, stream>>>(x_v, Wr2T, Hb, N_V);
  linear_mfma<<<(N_U + LM - 1) / LM, 256, 0, stream>>>(x_u, Wr1T, Hb + (size_t)N_V * D, N_U);

  partition_kernel<<<(ETOT + PCHUNK - 1) / PCHUNK, 256, 0, stream>>>(
      e1, e2, bucketCursor, recs);
  bucket_scan<<<1, 256, 0, stream>>>(bucketCursor, bucketBase);
  bucket_fill<<<NBUCK, 512, 0, stream>>>(recs, bucketCursor, bucketBase, row_ptr, colA);

  aggregate_kernel<<<N_V / 4, 256, 0, stream>>>(Hb, row_ptr, colA, SumB, MxB);

  epilogue_mfma<<<(N_V + EM - 1) / EM, 256, 0, stream>>>(
      (const unsigned short*)SumB, (const unsigned short*)MxB, row_ptr,
      Wg16, b_gate, Wa16, b_aggr, out);
}